// Round 1
// baseline (80.094 us; speedup 1.0000x reference)
//
#include <hip/hip_runtime.h>

// Elementwise: out = (idx even) ? sin(x) : cos(x)
// 4096 x 8192 f32 + i32 -> f32. Memory-bound: 384 MiB traffic, ~62 us floor @ 6.3 TB/s.

__global__ void __launch_bounds__(256) sincos_sel_kernel(
    const float4* __restrict__ x,
    const int4*  __restrict__ idx,
    float4* __restrict__ out,
    int n4)
{
    const int stride = gridDim.x * blockDim.x;
    for (int i = blockIdx.x * blockDim.x + threadIdx.x; i < n4; i += stride) {
        float4 xv = x[i];
        int4   iv = idx[i];
        float4 o;
        // idx >= 0 always, so (idx % 2 == 0) <=> ((idx & 1) == 0)
        o.x = (iv.x & 1) ? __cosf(xv.x) : __sinf(xv.x);
        o.y = (iv.y & 1) ? __cosf(xv.y) : __sinf(xv.y);
        o.z = (iv.z & 1) ? __cosf(xv.z) : __sinf(xv.z);
        o.w = (iv.w & 1) ? __cosf(xv.w) : __sinf(xv.w);
        out[i] = o;
    }
}

extern "C" void kernel_launch(void* const* d_in, const int* in_sizes, int n_in,
                              void* d_out, int out_size, void* d_ws, size_t ws_size,
                              hipStream_t stream)
{
    const float* x   = (const float*)d_in[0];
    const int*   idx = (const int*)d_in[1];
    float*       out = (float*)d_out;

    const int n  = in_sizes[0];      // 33,554,432 (divisible by 4)
    const int n4 = n >> 2;           // 8,388,608 float4 chunks

    const int block = 256;
    const int grid  = 2048;          // 256 CUs x 8 blocks/CU; grid-stride covers rest

    sincos_sel_kernel<<<grid, block, 0, stream>>>(
        (const float4*)x, (const int4*)idx, (float4*)out, n4);
}

// Round 2
// 66.191 us; speedup vs baseline: 1.2100x; 1.2100x over previous
//
#include <hip/hip_runtime.h>

// out = (idx even) ? sin(x) : cos(x), 4096x8192 f32/i32.
// Memory-bound. Levers this round:
//  - nontemporal stores: output never re-read -> keep 256 MiB of inputs L3-resident
//  - 4x batched loads per thread for memory-level parallelism (was 2 loads in flight)
//  - single v_sin_f32 in revolutions: cos(x) = sin(x + 0.25 rev)

typedef float vfloat4 __attribute__((ext_vector_type(4)));
typedef int   vint4   __attribute__((ext_vector_type(4)));

__device__ __forceinline__ float sincos_sel(float x, int odd) {
    const float INV2PI = 0.15915493667125702f;  // 1/(2*pi)
    // odd -> +0.25 revolutions (= +pi/2 radians) turns sin into cos
    float t = __builtin_fmaf(x, INV2PI, odd ? 0.25f : 0.0f);
    return __builtin_amdgcn_sinf(t);            // v_sin_f32: sin(t * 2*pi)
}

__global__ void __launch_bounds__(256) sincos_sel_kernel(
    const vfloat4* __restrict__ x,
    const vint4*  __restrict__ idx,
    vfloat4* __restrict__ out,
    int n4)
{
    const int tid    = blockIdx.x * blockDim.x + threadIdx.x;
    const int stride = gridDim.x * blockDim.x;

    int i = tid;
    // main: 4 independent vec4 chunks per iteration -> 8 loads in flight
    for (; i + 3 * stride < n4; i += 4 * stride) {
        vfloat4 x0 = x[i];
        vfloat4 x1 = x[i +     stride];
        vfloat4 x2 = x[i + 2 * stride];
        vfloat4 x3 = x[i + 3 * stride];
        vint4   d0 = idx[i];
        vint4   d1 = idx[i +     stride];
        vint4   d2 = idx[i + 2 * stride];
        vint4   d3 = idx[i + 3 * stride];

        vfloat4 o0, o1, o2, o3;
        #pragma unroll
        for (int j = 0; j < 4; ++j) {
            o0[j] = sincos_sel(x0[j], d0[j] & 1);
            o1[j] = sincos_sel(x1[j], d1[j] & 1);
            o2[j] = sincos_sel(x2[j], d2[j] & 1);
            o3[j] = sincos_sel(x3[j], d3[j] & 1);
        }
        __builtin_nontemporal_store(o0, &out[i]);
        __builtin_nontemporal_store(o1, &out[i +     stride]);
        __builtin_nontemporal_store(o2, &out[i + 2 * stride]);
        __builtin_nontemporal_store(o3, &out[i + 3 * stride]);
    }
    // tail
    for (; i < n4; i += stride) {
        vfloat4 xv = x[i];
        vint4   dv = idx[i];
        vfloat4 o;
        #pragma unroll
        for (int j = 0; j < 4; ++j) o[j] = sincos_sel(xv[j], dv[j] & 1);
        __builtin_nontemporal_store(o, &out[i]);
    }
}

extern "C" void kernel_launch(void* const* d_in, const int* in_sizes, int n_in,
                              void* d_out, int out_size, void* d_ws, size_t ws_size,
                              hipStream_t stream)
{
    const vfloat4* x   = (const vfloat4*)d_in[0];
    const vint4*   idx = (const vint4*)d_in[1];
    vfloat4*       out = (vfloat4*)d_out;

    const int n  = in_sizes[0];   // 33,554,432
    const int n4 = n >> 2;        // 8,388,608 vec4 chunks

    const int block = 256;
    const int grid  = 2048;       // 8 blocks/CU x 256 CUs; 16 chunks/thread

    sincos_sel_kernel<<<grid, block, 0, stream>>>(x, idx, out, n4);
}